// Round 7
// baseline (514716.113 us; speedup 1.0000x reference)
//
#include <hip/hip_runtime.h>

// ---------------------------------------------------------------------------
// RNN_69526930588180: 3-layer SimpleRNN (tanh), B=256, T=256, D=64, H=512.
//
// Round 7 = round 6 with the sync machinery de-serialized:
//  * Counters (64 atomic adds + 32 RMW pollers per step on ONE cache line,
//    ~2-3k cyc of atomic-unit queueing) -> 64 per-wave done-FLAGS in distinct
//    64B lines. Publish = one plain store after the wave's own vmcnt(0).
//    Detect = one 64-lane vector load + __all(tag match) — zero atomics.
//  * Cbuf parity double-buffer -> ONE __syncthreads per step (barrier(t+1)
//    orders combine-reads(t) before MFMA-writes(t+2)).
//  * Cache scopes unchanged (proven r6/r2): fast(same-XCD) = sc0 everywhere;
//    slow = sc0 sc1 everywhere. Startup XCC_ID handshake picks the path.
// Flags are per-(layer,t) slots, value 0x5A5A0000+t (never collides with the
// 0xAA poison), written exactly once -> no reset, no WAR.
// ---------------------------------------------------------------------------

typedef unsigned short u16;
typedef unsigned int   u32;

typedef __attribute__((ext_vector_type(8))) short short8;
typedef __attribute__((ext_vector_type(4))) float f32x4;
typedef __attribute__((ext_vector_type(4))) int   i32x4;

#define N_B 256
#define N_T 256
#define N_D 64
#define N_H 512
#define GB  16   // batch groups
#define GC  16   // column groups (WGs per bg)
#define BC  16   // rows per group
#define HC  32   // cols per WG
#define FLG_STRIDE 16  // dwords between flags (64 B -> distinct cache lines)

__device__ __forceinline__ u16 f2bf(float f) {
  union { float f; u32 u; } v; v.f = f;
  u32 u = v.u;
  u += 0x7fffu + ((u >> 16) & 1u);   // RNE
  return (u16)(u >> 16);
}
__device__ __forceinline__ float bf2f(u16 h) {
  union { u32 u; float f; } v; v.u = ((u32)h) << 16;
  return v.f;
}
__device__ __forceinline__ short8 ld8(const u16* p) { return *(const short8*)p; }
__device__ __forceinline__ short8 cvt8(const float* p) {
  short8 r;
#pragma unroll
  for (int j = 0; j < 8; ++j) r[j] = (short)f2bf(p[j]);
  return r;
}
__device__ __forceinline__ short8 as_s8(i32x4 v) {
  union { i32x4 i; short8 s; } u; u.i = v; return u.s;
}
// tanh(x) = 1 - 2/(exp(2x)+1); clamp (saturated anyway) to avoid inf.
__device__ __forceinline__ float fast_tanh(float x) {
  float xc = fminf(fmaxf(x, -9.f), 9.f);
  float e  = __builtin_amdgcn_exp2f(xc * 2.8853900817779268f);
  return 1.f - 2.f * __builtin_amdgcn_rcpf(e + 1.f);
}
// Atomic-RMW read (add 0, return old): coherence-point read. Startup only.
__device__ __forceinline__ u32 rmw_read(u32* p) {
  u32 v, z = 0;
  asm volatile("global_atomic_add %0, %1, %2, off sc0\n\ts_waitcnt vmcnt(0)"
               : "=v"(v) : "v"(p), "v"(z) : "memory");
  return v;
}

// 16 batched A-fragment loads (row fixed, k = kt*32 + quad*8), one vmcnt.
__device__ __forceinline__ void load_frags16_fast(const u16* p, i32x4 f[16]) {
  asm volatile(
      "global_load_dwordx4 %0, %16, off sc0\n\t"
      "global_load_dwordx4 %1, %16, off offset:64 sc0\n\t"
      "global_load_dwordx4 %2, %16, off offset:128 sc0\n\t"
      "global_load_dwordx4 %3, %16, off offset:192 sc0\n\t"
      "global_load_dwordx4 %4, %16, off offset:256 sc0\n\t"
      "global_load_dwordx4 %5, %16, off offset:320 sc0\n\t"
      "global_load_dwordx4 %6, %16, off offset:384 sc0\n\t"
      "global_load_dwordx4 %7, %16, off offset:448 sc0\n\t"
      "global_load_dwordx4 %8, %16, off offset:512 sc0\n\t"
      "global_load_dwordx4 %9, %16, off offset:576 sc0\n\t"
      "global_load_dwordx4 %10, %16, off offset:640 sc0\n\t"
      "global_load_dwordx4 %11, %16, off offset:704 sc0\n\t"
      "global_load_dwordx4 %12, %16, off offset:768 sc0\n\t"
      "global_load_dwordx4 %13, %16, off offset:832 sc0\n\t"
      "global_load_dwordx4 %14, %16, off offset:896 sc0\n\t"
      "global_load_dwordx4 %15, %16, off offset:960 sc0\n\t"
      "s_waitcnt vmcnt(0)"
      : "=&v"(f[0]), "=&v"(f[1]), "=&v"(f[2]), "=&v"(f[3]),
        "=&v"(f[4]), "=&v"(f[5]), "=&v"(f[6]), "=&v"(f[7]),
        "=&v"(f[8]), "=&v"(f[9]), "=&v"(f[10]), "=&v"(f[11]),
        "=&v"(f[12]), "=&v"(f[13]), "=&v"(f[14]), "=&v"(f[15])
      : "v"(p) : "memory");
}
__device__ __forceinline__ void load_frags16_slow(const u16* p, i32x4 f[16]) {
  asm volatile(
      "global_load_dwordx4 %0, %16, off sc0 sc1\n\t"
      "global_load_dwordx4 %1, %16, off offset:64 sc0 sc1\n\t"
      "global_load_dwordx4 %2, %16, off offset:128 sc0 sc1\n\t"
      "global_load_dwordx4 %3, %16, off offset:192 sc0 sc1\n\t"
      "global_load_dwordx4 %4, %16, off offset:256 sc0 sc1\n\t"
      "global_load_dwordx4 %5, %16, off offset:320 sc0 sc1\n\t"
      "global_load_dwordx4 %6, %16, off offset:384 sc0 sc1\n\t"
      "global_load_dwordx4 %7, %16, off offset:448 sc0 sc1\n\t"
      "global_load_dwordx4 %8, %16, off offset:512 sc0 sc1\n\t"
      "global_load_dwordx4 %9, %16, off offset:576 sc0 sc1\n\t"
      "global_load_dwordx4 %10, %16, off offset:640 sc0 sc1\n\t"
      "global_load_dwordx4 %11, %16, off offset:704 sc0 sc1\n\t"
      "global_load_dwordx4 %12, %16, off offset:768 sc0 sc1\n\t"
      "global_load_dwordx4 %13, %16, off offset:832 sc0 sc1\n\t"
      "global_load_dwordx4 %14, %16, off offset:896 sc0 sc1\n\t"
      "global_load_dwordx4 %15, %16, off offset:960 sc0 sc1\n\t"
      "s_waitcnt vmcnt(0)"
      : "=&v"(f[0]), "=&v"(f[1]), "=&v"(f[2]), "=&v"(f[3]),
        "=&v"(f[4]), "=&v"(f[5]), "=&v"(f[6]), "=&v"(f[7]),
        "=&v"(f[8]), "=&v"(f[9]), "=&v"(f[10]), "=&v"(f[11]),
        "=&v"(f[12]), "=&v"(f[13]), "=&v"(f[14]), "=&v"(f[15])
      : "v"(p) : "memory");
}

// One layer. in_ptr: L0 ? const float* x [B,T,64] : const u16* seq_in [T,B,512].
// out_seq: u16 [T,B,512]. flags: per-layer, [bg][t][64 waves] at 64B stride.
// hsk: 2*GB (arrive count, XCD mask), zeroed before launch.
template <bool L0>
__global__ __launch_bounds__(256, 1)
void rec_kernel(const void* __restrict__ in_ptr, u16* __restrict__ out_seq,
                const float* __restrict__ Wx, const float* __restrict__ Wh,
                const float* __restrict__ bias, u32* __restrict__ flags,
                u32* __restrict__ hsk) {
  constexpr int KIN = L0 ? N_D : N_H;
  // Swizzle: bg's 16 WGs share blockIdx%8 (XCD round-robin; verified r6).
  const int c8   = blockIdx.x & 7;
  const int s    = blockIdx.x >> 3;         // 0..31
  const int i    = c8 + 8 * (s >> 4);       // batch group 0..15
  const int j    = s & 15;                  // column group 0..15
  const int tid  = threadIdx.x;
  const int lane = tid & 63;
  const int w    = tid >> 6;
  const int quad = lane >> 4;
  const int l16  = lane & 15;
  const int gemm = w >> 1;            // 0: recurrent h@Wh (waves 0-1), 1: input proj
  const int nt   = w & 1;
  const int n_local = nt * 16 + l16;

  __shared__ u16   WhT[HC][N_H];      // [n][k], k rotated by 8*n
  __shared__ u16   WxT[HC][KIN];
  __shared__ float bsh[HC];
  __shared__ float Cbuf[2][2][16][33]; // [gemm][parity][row][col]
  __shared__ u32   fastsh;

  // ---- startup handshake: are all 16 WGs of bg i on one XCD? ----
  u32 xcc;
  asm volatile("s_getreg_b32 %0, hwreg(HW_REG_XCC_ID)" : "=s"(xcc));
  if (tid == 0) {
    __hip_atomic_fetch_or(&hsk[GB + i], 1u << (xcc & 7), __ATOMIC_RELAXED,
                          __HIP_MEMORY_SCOPE_AGENT);
    asm volatile("s_waitcnt vmcnt(0)" ::: "memory");
    __hip_atomic_fetch_add(&hsk[i], 1u, __ATOMIC_RELAXED,
                           __HIP_MEMORY_SCOPE_AGENT);
  }

  // Stage weight slices while the handshake propagates.
  for (int e = tid; e < HC * N_H; e += 256) {
    int n = e & 31, k = e >> 5;
    WhT[n][(k + 8 * n) & (N_H - 1)] = f2bf(Wh[k * N_H + j * HC + n]);
  }
  for (int e = tid; e < HC * KIN; e += 256) {
    int n = e & 31, k = e >> 5;
    WxT[n][(k + 8 * n) & (KIN - 1)] = f2bf(Wx[k * N_H + j * HC + n]);
  }
  if (tid < HC) bsh[tid] = bias[j * HC + tid];

  if (tid == 0) {
    bool f = false;
    u32 it = 0;
    while (rmw_read(&hsk[i]) < (u32)GC) {
      __builtin_amdgcn_s_sleep(1);
      if (++it > (1u << 22)) break;
    }
    if (it <= (1u << 22)) {
      u32 m = rmw_read(&hsk[GB + i]);
      f = (m != 0u) && ((m & (m - 1u)) == 0u);
    }
    fastsh = f ? 1u : 0u;
  }
  __syncthreads();
  const bool fast = (fastsh == 1u);

  // Per-wave flag slot this WG publishes; lane-indexed slots it polls.
  u32* my_flag   = flags + ((size_t)i * N_T * 64 + (size_t)(j * 4 + w)) * FLG_STRIDE;
  const u32* poll_base = flags + ((size_t)i * N_T * 64 + (size_t)lane) * FLG_STRIDE;
  bool dead = false;

  for (int t = 0; t < N_T; ++t) {
    const int par = t & 1;
    f32x4 acc = {0.f, 0.f, 0.f, 0.f};

    if (gemm == 1) {
      // ---- input projection (off critical path) ----
      f32x4 a0 = {0.f, 0.f, 0.f, 0.f}, a1 = {0.f, 0.f, 0.f, 0.f};
      if (L0) {
        const float* xp = (const float*)in_ptr +
            ((size_t)(i * BC + l16) * N_T + t) * N_D + quad * 8;
        short8 f0 = cvt8(xp), f1 = cvt8(xp + 32);
        a0 = __builtin_amdgcn_mfma_f32_16x16x32_bf16(
            f0, ld8(&WxT[n_local][(quad * 8 + 8 * n_local) & (KIN - 1)]), a0, 0, 0, 0);
        a1 = __builtin_amdgcn_mfma_f32_16x16x32_bf16(
            f1, ld8(&WxT[n_local][(32 + quad * 8 + 8 * n_local) & (KIN - 1)]), a1, 0, 0, 0);
      } else {
        const u16* sp = (const u16*)in_ptr +
            ((size_t)t * N_B + i * BC + l16) * N_H + quad * 8;
#pragma unroll
        for (int kt = 0; kt < KIN / 32; kt += 2) {
          a0 = __builtin_amdgcn_mfma_f32_16x16x32_bf16(
              ld8(sp + kt * 32),
              ld8(&WxT[n_local][(kt * 32 + quad * 8 + 8 * n_local) & (KIN - 1)]), a0, 0, 0, 0);
          a1 = __builtin_amdgcn_mfma_f32_16x16x32_bf16(
              ld8(sp + (kt + 1) * 32),
              ld8(&WxT[n_local][((kt + 1) * 32 + quad * 8 + 8 * n_local) & (KIN - 1)]), a1, 0, 0, 0);
        }
      }
#pragma unroll
      for (int e = 0; e < 4; ++e) acc[e] = a0[e] + a1[e];
      int rowb = quad * 4;
      Cbuf[1][par][rowb + 0][n_local] = acc[0];
      Cbuf[1][par][rowb + 1][n_local] = acc[1];
      Cbuf[1][par][rowb + 2][n_local] = acc[2];
      Cbuf[1][par][rowb + 3][n_local] = acc[3];
    } else {
      // ---- recurrent h_{t-1}@Wh ----
      if (t > 0) {
        // Poll: lane k checks flag k (64 distinct lines, one parallel load).
        if (!dead) {
          const u32* fp = poll_base + (size_t)(t - 1) * 64 * FLG_STRIDE;
          const u32 tag = 0x5A5A0000u + (u32)(t - 1);
          u32 it = 0;
          for (;;) {
            u32 v;
            if (fast) {
              asm volatile("global_load_dword %0, %1, off sc0\n\ts_waitcnt vmcnt(0)"
                           : "=v"(v) : "v"(fp) : "memory");
            } else {
              asm volatile("global_load_dword %0, %1, off sc0 sc1\n\ts_waitcnt vmcnt(0)"
                           : "=v"(v) : "v"(fp) : "memory");
            }
            if (__all((int)(v == tag))) break;
            if (++it > (1u << 20)) { dead = true; break; }
            if (it > 16) __builtin_amdgcn_s_sleep(1);
          }
        }
        const u16* ap = out_seq +
            ((size_t)(t - 1) * N_B + i * BC + l16) * N_H + quad * 8;
        i32x4 fr[16];
        if (fast) load_frags16_fast(ap, fr);
        else      load_frags16_slow(ap, fr);
        f32x4 a0 = {0.f, 0.f, 0.f, 0.f}, a1 = {0.f, 0.f, 0.f, 0.f};
#pragma unroll
        for (int kt = 0; kt < 16; kt += 2) {
          a0 = __builtin_amdgcn_mfma_f32_16x16x32_bf16(
              as_s8(fr[kt]),
              ld8(&WhT[n_local][(kt * 32 + quad * 8 + 8 * n_local) & (N_H - 1)]), a0, 0, 0, 0);
          a1 = __builtin_amdgcn_mfma_f32_16x16x32_bf16(
              as_s8(fr[kt + 1]),
              ld8(&WhT[n_local][((kt + 1) * 32 + quad * 8 + 8 * n_local) & (N_H - 1)]), a1, 0, 0, 0);
        }
#pragma unroll
        for (int e = 0; e < 4; ++e) acc[e] = a0[e] + a1[e];
      }
      int rowb = quad * 4;
      Cbuf[0][par][rowb + 0][n_local] = acc[0];
      Cbuf[0][par][rowb + 1][n_local] = acc[1];
      Cbuf[0][par][rowb + 2][n_local] = acc[2];
      Cbuf[0][par][rowb + 3][n_local] = acc[3];
    }

    __syncthreads();  // the ONLY per-step barrier (parity handles WAR)

    // ---- combine: u = h@Wh + x@Wx + b; h = tanh(u); publish wave flag ----
    {
      int r   = tid >> 4;           // wave w covers rows 4w..4w+3
      int c0i = (tid & 15) * 2;
      float u0 = Cbuf[0][par][r][c0i]     + Cbuf[1][par][r][c0i]     + bsh[c0i];
      float u1 = Cbuf[0][par][r][c0i + 1] + Cbuf[1][par][r][c0i + 1] + bsh[c0i + 1];
      u32 pk = (u32)f2bf(fast_tanh(u0)) | ((u32)f2bf(fast_tanh(u1)) << 16);
      u32* dst = (u32*)&out_seq[((size_t)t * N_B + i * BC + r) * N_H + j * HC + c0i];
      if (fast) {
        asm volatile("global_store_dword %0, %1, off sc0" :: "v"(dst), "v"(pk) : "memory");
      } else {
        asm volatile("global_store_dword %0, %1, off sc0 sc1" :: "v"(dst), "v"(pk) : "memory");
      }
    }
    // Per-wave publish: this wave's 64 h-stores acked, then one flag store.
    asm volatile("s_waitcnt vmcnt(0)" ::: "memory");
    if (lane == 0) {
      u32 tagv = 0x5A5A0000u + (u32)t;
      u32* fp = my_flag + (size_t)t * 64 * FLG_STRIDE;
      if (fast) {
        asm volatile("global_store_dword %0, %1, off sc0" :: "v"(fp), "v"(tagv) : "memory");
      } else {
        asm volatile("global_store_dword %0, %1, off sc0 sc1" :: "v"(fp), "v"(tagv) : "memory");
      }
    }
    // no trailing barrier: parity double-buffer makes next-iter writes safe
  }
}

// out[b] = seq2[T-1][b][:] . Wf + bf
__global__ void head_kernel(const u16* __restrict__ seq2, const float* __restrict__ Wf,
                            const float* __restrict__ bf, float* __restrict__ out) {
  int b    = blockIdx.x;
  int lane = threadIdx.x;  // 64
  const u16* hrow = seq2 + ((size_t)(N_T - 1) * N_B + b) * N_H;
  float s = 0.f;
#pragma unroll
  for (int r = 0; r < N_H / 64; ++r) {
    int idx = lane * 8 + r;
    s += bf2f(hrow[idx]) * Wf[idx];
  }
#pragma unroll
  for (int off = 32; off > 0; off >>= 1) s += __shfl_down(s, off);
  if (lane == 0) out[b] = s + bf[0];
}

extern "C" void kernel_launch(void* const* d_in, const int* in_sizes, int n_in,
                              void* d_out, int out_size, void* d_ws, size_t ws_size,
                              hipStream_t stream) {
  const float* x   = (const float*)d_in[0];
  const float* Wx0 = (const float*)d_in[1];
  const float* Wh0 = (const float*)d_in[2];
  const float* b0  = (const float*)d_in[3];
  const float* Wx1 = (const float*)d_in[4];
  const float* Wh1 = (const float*)d_in[5];
  const float* b1  = (const float*)d_in[6];
  const float* Wx2 = (const float*)d_in[7];
  const float* Wh2 = (const float*)d_in[8];
  const float* b2  = (const float*)d_in[9];
  const float* Wf  = (const float*)d_in[10];
  const float* bf  = (const float*)d_in[11];
  float* out = (float*)d_out;

  const size_t SEQ_BYTES = (size_t)N_T * N_B * N_H * sizeof(u16);        // 67,108,864
  const size_t FLG_U32   = (size_t)GB * N_T * 64 * FLG_STRIDE;           // 4,194,304
  const size_t FLG_BYTES = FLG_U32 * sizeof(u32);                        // 16,777,216
  const size_t HSK_U32   = (size_t)3 * 2 * GB;                           // 96
  if (ws_size < 2 * SEQ_BYTES + 3 * FLG_BYTES + HSK_U32 * sizeof(u32)) return;

  char* ws   = (char*)d_ws;
  u16* seqA  = (u16*)(ws);
  u16* seqB  = (u16*)(ws + SEQ_BYTES);
  u32* flg0  = (u32*)(ws + 2 * SEQ_BYTES);
  u32* flg1  = flg0 + FLG_U32;
  u32* flg2  = flg1 + FLG_U32;
  u32* hsk   = flg2 + FLG_U32;

  (void)hipMemsetAsync(hsk, 0, HSK_U32 * sizeof(u32), stream);

  rec_kernel<true ><<<256, 256, 0, stream>>>((const void*)x,    seqA, Wx0, Wh0, b0,
                                             flg0, hsk);
  rec_kernel<false><<<256, 256, 0, stream>>>((const void*)seqA, seqB, Wx1, Wh1, b1,
                                             flg1, hsk + 2 * GB);
  rec_kernel<false><<<256, 256, 0, stream>>>((const void*)seqB, seqA, Wx2, Wh2, b2,
                                             flg2, hsk + 4 * GB);
  head_kernel<<<N_B, 64, 0, stream>>>(seqA, Wf, bf, out);
}

// Round 8
// 2337.240 us; speedup vs baseline: 220.2239x; 220.2239x over previous
//
#include <hip/hip_runtime.h>

// ---------------------------------------------------------------------------
// RNN_69526930588180: 3-layer SimpleRNN (tanh), B=256, T=256, D=64, H=512.
//
// Round 8 = round 6 (proven: atomic counter + RMW poll, XCD-local fast path,
// 2462 us) with the critical chain shortened:
//  * rec waves (0-1) do the combine IN-REGISTER for their own C tiles and
//    store h directly (4x global_store_short / lane) -> deletes the second
//    combine phase, one barrier, and half the Cbuf LDS traffic.
//  * proj waves (2-3) only: proj MFMA -> Cbuf[parity] -> barrier (pace-lock).
//  * publishers 64 -> 32 (rec waves only, one atomic per wave after its own
//    vmcnt(0)); CNT_TARGET = 32. Poll mechanism identical to r6 (RMW read,
//    s_sleep(1) cadence) — r7 proved plain-store flags + wide polls livelock
//    (reader flood starves non-atomic writers); atomics are FIFO-fair.
//  * Cbuf parity double-buffer makes the single barrier sufficient (write(t+2)
//    to a slot happens after barrier(t+1), which follows combine-reads(t)).
// ---------------------------------------------------------------------------

typedef unsigned short u16;
typedef unsigned int   u32;

typedef __attribute__((ext_vector_type(8))) short short8;
typedef __attribute__((ext_vector_type(4))) float f32x4;
typedef __attribute__((ext_vector_type(4))) int   i32x4;

#define N_B 256
#define N_T 256
#define N_D 64
#define N_H 512
#define GB  16   // batch groups
#define GC  16   // column groups (WGs per bg)
#define BC  16   // rows per group
#define HC  32   // cols per WG
#define CNT_TARGET 32  // 16 WGs x 2 rec waves publish per step

__device__ __forceinline__ u16 f2bf(float f) {
  union { float f; u32 u; } v; v.f = f;
  u32 u = v.u;
  u += 0x7fffu + ((u >> 16) & 1u);   // RNE
  return (u16)(u >> 16);
}
__device__ __forceinline__ float bf2f(u16 h) {
  union { u32 u; float f; } v; v.u = ((u32)h) << 16;
  return v.f;
}
__device__ __forceinline__ short8 ld8(const u16* p) { return *(const short8*)p; }
__device__ __forceinline__ short8 cvt8(const float* p) {
  short8 r;
#pragma unroll
  for (int j = 0; j < 8; ++j) r[j] = (short)f2bf(p[j]);
  return r;
}
__device__ __forceinline__ short8 as_s8(i32x4 v) {
  union { i32x4 i; short8 s; } u; u.i = v; return u.s;
}
// tanh(x) = 1 - 2/(exp(2x)+1); clamp (saturated anyway) to avoid inf.
__device__ __forceinline__ float fast_tanh(float x) {
  float xc = fminf(fmaxf(x, -9.f), 9.f);
  float e  = __builtin_amdgcn_exp2f(xc * 2.8853900817779268f);
  return 1.f - 2.f * __builtin_amdgcn_rcpf(e + 1.f);
}
// Atomic-RMW read (add 0, return old): FIFO-fair coherence-point read (r6-proven).
__device__ __forceinline__ u32 rmw_read(u32* p) {
  u32 v, z = 0;
  asm volatile("global_atomic_add %0, %1, %2, off sc0\n\ts_waitcnt vmcnt(0)"
               : "=v"(v) : "v"(p), "v"(z) : "memory");
  return v;
}

// 16 batched A-fragment loads (row fixed, k = kt*32 + quad*8), one vmcnt.
__device__ __forceinline__ void load_frags16_fast(const u16* p, i32x4 f[16]) {
  asm volatile(
      "global_load_dwordx4 %0, %16, off sc0\n\t"
      "global_load_dwordx4 %1, %16, off offset:64 sc0\n\t"
      "global_load_dwordx4 %2, %16, off offset:128 sc0\n\t"
      "global_load_dwordx4 %3, %16, off offset:192 sc0\n\t"
      "global_load_dwordx4 %4, %16, off offset:256 sc0\n\t"
      "global_load_dwordx4 %5, %16, off offset:320 sc0\n\t"
      "global_load_dwordx4 %6, %16, off offset:384 sc0\n\t"
      "global_load_dwordx4 %7, %16, off offset:448 sc0\n\t"
      "global_load_dwordx4 %8, %16, off offset:512 sc0\n\t"
      "global_load_dwordx4 %9, %16, off offset:576 sc0\n\t"
      "global_load_dwordx4 %10, %16, off offset:640 sc0\n\t"
      "global_load_dwordx4 %11, %16, off offset:704 sc0\n\t"
      "global_load_dwordx4 %12, %16, off offset:768 sc0\n\t"
      "global_load_dwordx4 %13, %16, off offset:832 sc0\n\t"
      "global_load_dwordx4 %14, %16, off offset:896 sc0\n\t"
      "global_load_dwordx4 %15, %16, off offset:960 sc0\n\t"
      "s_waitcnt vmcnt(0)"
      : "=&v"(f[0]), "=&v"(f[1]), "=&v"(f[2]), "=&v"(f[3]),
        "=&v"(f[4]), "=&v"(f[5]), "=&v"(f[6]), "=&v"(f[7]),
        "=&v"(f[8]), "=&v"(f[9]), "=&v"(f[10]), "=&v"(f[11]),
        "=&v"(f[12]), "=&v"(f[13]), "=&v"(f[14]), "=&v"(f[15])
      : "v"(p) : "memory");
}
__device__ __forceinline__ void load_frags16_slow(const u16* p, i32x4 f[16]) {
  asm volatile(
      "global_load_dwordx4 %0, %16, off sc0 sc1\n\t"
      "global_load_dwordx4 %1, %16, off offset:64 sc0 sc1\n\t"
      "global_load_dwordx4 %2, %16, off offset:128 sc0 sc1\n\t"
      "global_load_dwordx4 %3, %16, off offset:192 sc0 sc1\n\t"
      "global_load_dwordx4 %4, %16, off offset:256 sc0 sc1\n\t"
      "global_load_dwordx4 %5, %16, off offset:320 sc0 sc1\n\t"
      "global_load_dwordx4 %6, %16, off offset:384 sc0 sc1\n\t"
      "global_load_dwordx4 %7, %16, off offset:448 sc0 sc1\n\t"
      "global_load_dwordx4 %8, %16, off offset:512 sc0 sc1\n\t"
      "global_load_dwordx4 %9, %16, off offset:576 sc0 sc1\n\t"
      "global_load_dwordx4 %10, %16, off offset:640 sc0 sc1\n\t"
      "global_load_dwordx4 %11, %16, off offset:704 sc0 sc1\n\t"
      "global_load_dwordx4 %12, %16, off offset:768 sc0 sc1\n\t"
      "global_load_dwordx4 %13, %16, off offset:832 sc0 sc1\n\t"
      "global_load_dwordx4 %14, %16, off offset:896 sc0 sc1\n\t"
      "global_load_dwordx4 %15, %16, off offset:960 sc0 sc1\n\t"
      "s_waitcnt vmcnt(0)"
      : "=&v"(f[0]), "=&v"(f[1]), "=&v"(f[2]), "=&v"(f[3]),
        "=&v"(f[4]), "=&v"(f[5]), "=&v"(f[6]), "=&v"(f[7]),
        "=&v"(f[8]), "=&v"(f[9]), "=&v"(f[10]), "=&v"(f[11]),
        "=&v"(f[12]), "=&v"(f[13]), "=&v"(f[14]), "=&v"(f[15])
      : "v"(p) : "memory");
}

// One layer. in_ptr: L0 ? const float* x [B,T,64] : const u16* seq_in [T,B,512].
// out_seq: u16 [T,B,512]. cnt: GB*N_T counters. hsk: 2*GB (arrive, mask).
template <bool L0>
__global__ __launch_bounds__(256, 1)
void rec_kernel(const void* __restrict__ in_ptr, u16* __restrict__ out_seq,
                const float* __restrict__ Wx, const float* __restrict__ Wh,
                const float* __restrict__ bias, u32* __restrict__ cnt,
                u32* __restrict__ hsk) {
  constexpr int KIN = L0 ? N_D : N_H;
  // Swizzle: bg's 16 WGs share blockIdx%8 (XCD round-robin; verified r6:
  // FETCH_SIZE collapsed 528->74 MB when the fast path engaged).
  const int c8   = blockIdx.x & 7;
  const int s    = blockIdx.x >> 3;         // 0..31
  const int i    = c8 + 8 * (s >> 4);       // batch group 0..15
  const int j    = s & 15;                  // column group 0..15
  const int tid  = threadIdx.x;
  const int lane = tid & 63;
  const int w    = tid >> 6;
  const int quad = lane >> 4;
  const int l16  = lane & 15;
  const int gemm = w >> 1;            // 0: recurrent+epilogue (waves 0-1), 1: proj
  const int nt   = w & 1;
  const int n_local = nt * 16 + l16;

  __shared__ u16   WhT[HC][N_H];      // [n][k], k rotated by 8*n
  __shared__ u16   WxT[HC][KIN];
  __shared__ float Cbuf[2][16][33];   // [parity][row][col] - proj results only
  __shared__ u32   fastsh;

  // ---- startup handshake: are all 16 WGs of bg i on one XCD? ----
  u32 xcc;
  asm volatile("s_getreg_b32 %0, hwreg(HW_REG_XCC_ID)" : "=s"(xcc));
  if (tid == 0) {
    __hip_atomic_fetch_or(&hsk[GB + i], 1u << (xcc & 7), __ATOMIC_RELAXED,
                          __HIP_MEMORY_SCOPE_AGENT);
    asm volatile("s_waitcnt vmcnt(0)" ::: "memory");
    __hip_atomic_fetch_add(&hsk[i], 1u, __ATOMIC_RELAXED,
                           __HIP_MEMORY_SCOPE_AGENT);
  }

  // Stage weight slices while the handshake propagates.
  for (int e = tid; e < HC * N_H; e += 256) {
    int n = e & 31, k = e >> 5;
    WhT[n][(k + 8 * n) & (N_H - 1)] = f2bf(Wh[k * N_H + j * HC + n]);
  }
  for (int e = tid; e < HC * KIN; e += 256) {
    int n = e & 31, k = e >> 5;
    WxT[n][(k + 8 * n) & (KIN - 1)] = f2bf(Wx[k * N_H + j * HC + n]);
  }
  const float bval = bias[j * HC + n_local];  // per-lane bias (col = n_local)

  if (tid == 0) {
    bool f = false;
    u32 it = 0;
    while (rmw_read(&hsk[i]) < (u32)GC) {
      __builtin_amdgcn_s_sleep(1);
      if (++it > (1u << 22)) break;
    }
    if (it <= (1u << 22)) {
      u32 m = rmw_read(&hsk[GB + i]);
      f = (m != 0u) && ((m & (m - 1u)) == 0u);
    }
    fastsh = f ? 1u : 0u;
  }
  __syncthreads();
  const bool fast = (fastsh == 1u);

  bool dead = false;

  for (int t = 0; t < N_T; ++t) {
    const int par = t & 1;
    f32x4 acc = {0.f, 0.f, 0.f, 0.f};

    if (gemm == 1) {
      // ---- proj waves: x_t@Wx -> Cbuf[par]; pace-locked by the barrier ----
      f32x4 a0 = {0.f, 0.f, 0.f, 0.f}, a1 = {0.f, 0.f, 0.f, 0.f};
      if (L0) {
        const float* xp = (const float*)in_ptr +
            ((size_t)(i * BC + l16) * N_T + t) * N_D + quad * 8;
        short8 f0 = cvt8(xp), f1 = cvt8(xp + 32);
        a0 = __builtin_amdgcn_mfma_f32_16x16x32_bf16(
            f0, ld8(&WxT[n_local][(quad * 8 + 8 * n_local) & (KIN - 1)]), a0, 0, 0, 0);
        a1 = __builtin_amdgcn_mfma_f32_16x16x32_bf16(
            f1, ld8(&WxT[n_local][(32 + quad * 8 + 8 * n_local) & (KIN - 1)]), a1, 0, 0, 0);
      } else {
        const u16* sp = (const u16*)in_ptr +
            ((size_t)t * N_B + i * BC + l16) * N_H + quad * 8;
#pragma unroll
        for (int kt = 0; kt < KIN / 32; kt += 2) {
          a0 = __builtin_amdgcn_mfma_f32_16x16x32_bf16(
              ld8(sp + kt * 32),
              ld8(&WxT[n_local][(kt * 32 + quad * 8 + 8 * n_local) & (KIN - 1)]), a0, 0, 0, 0);
          a1 = __builtin_amdgcn_mfma_f32_16x16x32_bf16(
              ld8(sp + (kt + 1) * 32),
              ld8(&WxT[n_local][((kt + 1) * 32 + quad * 8 + 8 * n_local) & (KIN - 1)]), a1, 0, 0, 0);
        }
      }
      int rowb = quad * 4;
      Cbuf[par][rowb + 0][n_local] = a0[0] + a1[0];
      Cbuf[par][rowb + 1][n_local] = a0[1] + a1[1];
      Cbuf[par][rowb + 2][n_local] = a0[2] + a1[2];
      Cbuf[par][rowb + 3][n_local] = a0[3] + a1[3];
    } else {
      // ---- rec waves: wait, load A, h_{t-1}@Wh ----
      if (t > 0) {
        if (lane == 0 && !dead) {
          u32* cp = &cnt[i * N_T + (t - 1)];
          u32 it = 0;
          for (;;) {
            u32 v;
            if (fast) {
              v = rmw_read(cp);
            } else {
              v = __hip_atomic_load(cp, __ATOMIC_RELAXED, __HIP_MEMORY_SCOPE_AGENT);
            }
            if (v >= (u32)CNT_TARGET) break;
            __builtin_amdgcn_s_sleep(1);
            if (++it > (1u << 22)) { dead = true; break; }
          }
        }
        const u16* ap = out_seq +
            ((size_t)(t - 1) * N_B + i * BC + l16) * N_H + quad * 8;
        i32x4 fr[16];
        if (fast) load_frags16_fast(ap, fr);
        else      load_frags16_slow(ap, fr);
        f32x4 a0 = {0.f, 0.f, 0.f, 0.f}, a1 = {0.f, 0.f, 0.f, 0.f};
#pragma unroll
        for (int kt = 0; kt < 16; kt += 2) {
          a0 = __builtin_amdgcn_mfma_f32_16x16x32_bf16(
              as_s8(fr[kt]),
              ld8(&WhT[n_local][(kt * 32 + quad * 8 + 8 * n_local) & (N_H - 1)]), a0, 0, 0, 0);
          a1 = __builtin_amdgcn_mfma_f32_16x16x32_bf16(
              as_s8(fr[kt + 1]),
              ld8(&WhT[n_local][((kt + 1) * 32 + quad * 8 + 8 * n_local) & (N_H - 1)]), a1, 0, 0, 0);
        }
#pragma unroll
        for (int e = 0; e < 4; ++e) acc[e] = a0[e] + a1[e];
      }
    }

    __syncthreads();  // the only per-step barrier: Cbuf[par] ready

    if (gemm == 0) {
      // ---- in-register combine: u = rec + proj + b; h = tanh(u); store ----
      // C layout (m89, HW-proven r2-r7): col = l16 (-> n_local), row = quad*4+r.
      u16* hdst = out_seq + ((size_t)t * N_B + i * BC + quad * 4) * N_H + j * HC + n_local;
      int rowb = quad * 4;
      u32 h0 = (u32)f2bf(fast_tanh(acc[0] + Cbuf[par][rowb + 0][n_local] + bval));
      u32 h1 = (u32)f2bf(fast_tanh(acc[1] + Cbuf[par][rowb + 1][n_local] + bval));
      u32 h2 = (u32)f2bf(fast_tanh(acc[2] + Cbuf[par][rowb + 2][n_local] + bval));
      u32 h3 = (u32)f2bf(fast_tanh(acc[3] + Cbuf[par][rowb + 3][n_local] + bval));
      if (fast) {
        asm volatile(
            "global_store_short %0, %1, off sc0\n\t"
            "global_store_short %0, %2, off offset:1024 sc0\n\t"
            "global_store_short %0, %3, off offset:2048 sc0\n\t"
            "global_store_short %0, %4, off offset:3072 sc0"
            :: "v"(hdst), "v"(h0), "v"(h1), "v"(h2), "v"(h3) : "memory");
      } else {
        asm volatile(
            "global_store_short %0, %1, off sc0 sc1\n\t"
            "global_store_short %0, %2, off offset:1024 sc0 sc1\n\t"
            "global_store_short %0, %3, off offset:2048 sc0 sc1\n\t"
            "global_store_short %0, %4, off offset:3072 sc0 sc1"
            :: "v"(hdst), "v"(h0), "v"(h1), "v"(h2), "v"(h3) : "memory");
      }
      // Publish: this wave's 16x16 tile acked at L2/LLC, then one atomic.
      asm volatile("s_waitcnt vmcnt(0)" ::: "memory");
      if (lane == 0) {
        u32* cp = &cnt[i * N_T + t];
        if (fast) {
          u32 one = 1u;
          asm volatile("global_atomic_add %0, %1, off" :: "v"(cp), "v"(one) : "memory");
        } else {
          __hip_atomic_fetch_add(cp, 1u, __ATOMIC_RELAXED, __HIP_MEMORY_SCOPE_AGENT);
        }
      }
    }
    // No trailing barrier: Cbuf parity + the next barrier handle WAR safety.
  }
}

// out[b] = seq2[T-1][b][:] . Wf + bf
__global__ void head_kernel(const u16* __restrict__ seq2, const float* __restrict__ Wf,
                            const float* __restrict__ bf, float* __restrict__ out) {
  int b    = blockIdx.x;
  int lane = threadIdx.x;  // 64
  const u16* hrow = seq2 + ((size_t)(N_T - 1) * N_B + b) * N_H;
  float s = 0.f;
#pragma unroll
  for (int r = 0; r < N_H / 64; ++r) {
    int idx = lane * 8 + r;
    s += bf2f(hrow[idx]) * Wf[idx];
  }
#pragma unroll
  for (int off = 32; off > 0; off >>= 1) s += __shfl_down(s, off);
  if (lane == 0) out[b] = s + bf[0];
}

extern "C" void kernel_launch(void* const* d_in, const int* in_sizes, int n_in,
                              void* d_out, int out_size, void* d_ws, size_t ws_size,
                              hipStream_t stream) {
  const float* x   = (const float*)d_in[0];
  const float* Wx0 = (const float*)d_in[1];
  const float* Wh0 = (const float*)d_in[2];
  const float* b0  = (const float*)d_in[3];
  const float* Wx1 = (const float*)d_in[4];
  const float* Wh1 = (const float*)d_in[5];
  const float* b1  = (const float*)d_in[6];
  const float* Wx2 = (const float*)d_in[7];
  const float* Wh2 = (const float*)d_in[8];
  const float* b2  = (const float*)d_in[9];
  const float* Wf  = (const float*)d_in[10];
  const float* bf  = (const float*)d_in[11];
  float* out = (float*)d_out;

  const size_t SEQ_BYTES = (size_t)N_T * N_B * N_H * sizeof(u16);  // 67,108,864
  const size_t CNT_U32   = (size_t)3 * GB * N_T;                   // 12,288
  const size_t HSK_U32   = (size_t)3 * 2 * GB;                     // 96
  if (ws_size < 2 * SEQ_BYTES + (CNT_U32 + HSK_U32) * sizeof(u32)) return;

  char* ws  = (char*)d_ws;
  u16* seqA = (u16*)(ws);
  u16* seqB = (u16*)(ws + SEQ_BYTES);
  u32* cnt  = (u32*)(ws + 2 * SEQ_BYTES);
  u32* hsk  = cnt + CNT_U32;

  (void)hipMemsetAsync(cnt, 0, (CNT_U32 + HSK_U32) * sizeof(u32), stream);

  rec_kernel<true ><<<256, 256, 0, stream>>>((const void*)x,    seqA, Wx0, Wh0, b0,
                                             cnt,              hsk);
  rec_kernel<false><<<256, 256, 0, stream>>>((const void*)seqA, seqB, Wx1, Wh1, b1,
                                             cnt + GB * N_T,   hsk + 2 * GB);
  rec_kernel<false><<<256, 256, 0, stream>>>((const void*)seqB, seqA, Wx2, Wh2, b2,
                                             cnt + 2 * GB * N_T, hsk + 4 * GB);
  head_kernel<<<N_B, 64, 0, stream>>>(seqA, Wf, bf, out);
}

// Round 9
// 1286.557 us; speedup vs baseline: 400.0724x; 1.8167x over previous
//
#include <hip/hip_runtime.h>

// ---------------------------------------------------------------------------
// RNN_69526930588180: 3-layer SimpleRNN (tanh), B=256, T=256, D=64, H=512.
//
// Round 9: LAYER-WAVEFRONT PIPELINE. One persistent kernel runs all 3 layers
// concurrently; sequential depth drops 768 -> 258 hops (hop latency measured
// sticky at ~3.2us across r6/r8; this attacks the hop COUNT instead).
//  * 192 WGs = 3 layers x 8 bg x 8 cg. Tile 32 rows x 64 cols. LDS: Wh 64KB +
//    Wx 64KB + Cbuf 17KB (~147KB) -> 1 WG/CU, all co-resident.
//  * waves 0-1 = recurrent h@Wh + combine + store + publish; waves 2-3 = proj.
//  * rec waves poll cnt[l][b][t-1]; proj waves (layers 1,2) poll cnt[l-1][b][t]
//    -> acyclic dependency DAG, deadlock-free; layer-0 proj free-runs.
//  * Sync/protocol carried VERBATIM from r8 (proven): FIFO-fair RMW polls +
//    atomic publish; fast(same-XCD)=sc0, slow=sc0 sc1; XCC_ID handshake
//    (now 24 arrivals/bg since cross-layer WGs communicate too).
// ---------------------------------------------------------------------------

typedef unsigned short u16;
typedef unsigned int   u32;

typedef __attribute__((ext_vector_type(8))) short short8;
typedef __attribute__((ext_vector_type(4))) float f32x4;
typedef __attribute__((ext_vector_type(4))) int   i32x4;

#define N_B 256
#define N_T 256
#define N_D 64
#define N_H 512
#define LAY 3
#define BG  8     // batch groups (32 rows each)
#define CGS 8     // col groups (64 cols each)
#define ROWS 32   // rows per bg
#define WCOL 64   // cols per WG
#define CNT_TGT 16   // 8 WGs x 2 rec waves publish per (layer,bg,t)
#define HSK_TGT 24   // 3 layers x 8 cg WGs per bg

__device__ __forceinline__ u16 f2bf(float f) {
  union { float f; u32 u; } v; v.f = f;
  u32 u = v.u;
  u += 0x7fffu + ((u >> 16) & 1u);   // RNE
  return (u16)(u >> 16);
}
__device__ __forceinline__ float bf2f(u16 h) {
  union { u32 u; float f; } v; v.u = ((u32)h) << 16;
  return v.f;
}
__device__ __forceinline__ short8 ld8(const u16* p) { return *(const short8*)p; }
__device__ __forceinline__ short8 cvt8(const float* p) {
  short8 r;
#pragma unroll
  for (int j = 0; j < 8; ++j) r[j] = (short)f2bf(p[j]);
  return r;
}
__device__ __forceinline__ short8 as_s8(i32x4 v) {
  union { i32x4 i; short8 s; } u; u.i = v; return u.s;
}
__device__ __forceinline__ float fast_tanh(float x) {
  float xc = fminf(fmaxf(x, -9.f), 9.f);
  float e  = __builtin_amdgcn_exp2f(xc * 2.8853900817779268f);
  return 1.f - 2.f * __builtin_amdgcn_rcpf(e + 1.f);
}
// FIFO-fair coherence-point read (r6/r8-proven).
__device__ __forceinline__ u32 rmw_read(u32* p) {
  u32 v, z = 0;
  asm volatile("global_atomic_add %0, %1, %2, off sc0\n\ts_waitcnt vmcnt(0)"
               : "=v"(v) : "v"(p), "v"(z) : "memory");
  return v;
}

// 16 batched A-fragment loads (row fixed, k = kt*32 + quad*8), one vmcnt.
__device__ __forceinline__ void load_frags16_fast(const u16* p, i32x4 f[16]) {
  asm volatile(
      "global_load_dwordx4 %0, %16, off sc0\n\t"
      "global_load_dwordx4 %1, %16, off offset:64 sc0\n\t"
      "global_load_dwordx4 %2, %16, off offset:128 sc0\n\t"
      "global_load_dwordx4 %3, %16, off offset:192 sc0\n\t"
      "global_load_dwordx4 %4, %16, off offset:256 sc0\n\t"
      "global_load_dwordx4 %5, %16, off offset:320 sc0\n\t"
      "global_load_dwordx4 %6, %16, off offset:384 sc0\n\t"
      "global_load_dwordx4 %7, %16, off offset:448 sc0\n\t"
      "global_load_dwordx4 %8, %16, off offset:512 sc0\n\t"
      "global_load_dwordx4 %9, %16, off offset:576 sc0\n\t"
      "global_load_dwordx4 %10, %16, off offset:640 sc0\n\t"
      "global_load_dwordx4 %11, %16, off offset:704 sc0\n\t"
      "global_load_dwordx4 %12, %16, off offset:768 sc0\n\t"
      "global_load_dwordx4 %13, %16, off offset:832 sc0\n\t"
      "global_load_dwordx4 %14, %16, off offset:896 sc0\n\t"
      "global_load_dwordx4 %15, %16, off offset:960 sc0\n\t"
      "s_waitcnt vmcnt(0)"
      : "=&v"(f[0]), "=&v"(f[1]), "=&v"(f[2]), "=&v"(f[3]),
        "=&v"(f[4]), "=&v"(f[5]), "=&v"(f[6]), "=&v"(f[7]),
        "=&v"(f[8]), "=&v"(f[9]), "=&v"(f[10]), "=&v"(f[11]),
        "=&v"(f[12]), "=&v"(f[13]), "=&v"(f[14]), "=&v"(f[15])
      : "v"(p) : "memory");
}
__device__ __forceinline__ void load_frags16_slow(const u16* p, i32x4 f[16]) {
  asm volatile(
      "global_load_dwordx4 %0, %16, off sc0 sc1\n\t"
      "global_load_dwordx4 %1, %16, off offset:64 sc0 sc1\n\t"
      "global_load_dwordx4 %2, %16, off offset:128 sc0 sc1\n\t"
      "global_load_dwordx4 %3, %16, off offset:192 sc0 sc1\n\t"
      "global_load_dwordx4 %4, %16, off offset:256 sc0 sc1\n\t"
      "global_load_dwordx4 %5, %16, off offset:320 sc0 sc1\n\t"
      "global_load_dwordx4 %6, %16, off offset:384 sc0 sc1\n\t"
      "global_load_dwordx4 %7, %16, off offset:448 sc0 sc1\n\t"
      "global_load_dwordx4 %8, %16, off offset:512 sc0 sc1\n\t"
      "global_load_dwordx4 %9, %16, off offset:576 sc0 sc1\n\t"
      "global_load_dwordx4 %10, %16, off offset:640 sc0 sc1\n\t"
      "global_load_dwordx4 %11, %16, off offset:704 sc0 sc1\n\t"
      "global_load_dwordx4 %12, %16, off offset:768 sc0 sc1\n\t"
      "global_load_dwordx4 %13, %16, off offset:832 sc0 sc1\n\t"
      "global_load_dwordx4 %14, %16, off offset:896 sc0 sc1\n\t"
      "global_load_dwordx4 %15, %16, off offset:960 sc0 sc1\n\t"
      "s_waitcnt vmcnt(0)"
      : "=&v"(f[0]), "=&v"(f[1]), "=&v"(f[2]), "=&v"(f[3]),
        "=&v"(f[4]), "=&v"(f[5]), "=&v"(f[6]), "=&v"(f[7]),
        "=&v"(f[8]), "=&v"(f[9]), "=&v"(f[10]), "=&v"(f[11]),
        "=&v"(f[12]), "=&v"(f[13]), "=&v"(f[14]), "=&v"(f[15])
      : "v"(p) : "memory");
}

#define MFMA16(a, b, c) __builtin_amdgcn_mfma_f32_16x16x32_bf16((a), (b), (c), 0, 0, 0)

// All 3 layers in one persistent kernel (layer-wavefront pipeline).
__global__ __launch_bounds__(256, 1)
void rnn_pipe(const float* __restrict__ x,
              const float* __restrict__ Wx0, const float* __restrict__ Wh0, const float* __restrict__ b0,
              const float* __restrict__ Wx1, const float* __restrict__ Wh1, const float* __restrict__ b1,
              const float* __restrict__ Wx2, const float* __restrict__ Wh2, const float* __restrict__ b2,
              u16* __restrict__ seq0, u16* __restrict__ seq1, u16* __restrict__ seq2,
              u32* __restrict__ cnt, u32* __restrict__ hsk) {
  const int b    = blockIdx.x & 7;          // batch group (XCD under %8 rr)
  const int rst  = blockIdx.x >> 3;         // 0..23
  const int layer = rst >> 3;               // 0..2
  const int j    = rst & 7;                 // col group
  const int tid  = threadIdx.x;
  const int lane = tid & 63;
  const int w    = tid >> 6;                // 0-1 rec, 2-3 proj
  const int quad = lane >> 4;
  const int l16  = lane & 15;
  const int half = w & 1;                   // 16-row sub-tile
  const bool is_rec = (w < 2);

  const float *Wx, *Wh, *bias; const u16 *in_seq = nullptr; u16 *out_seq;
  if (layer == 0)      { Wx = Wx0; Wh = Wh0; bias = b0; out_seq = seq0; }
  else if (layer == 1) { Wx = Wx1; Wh = Wh1; bias = b1; in_seq = seq0; out_seq = seq1; }
  else                 { Wx = Wx2; Wh = Wh2; bias = b2; in_seq = seq1; out_seq = seq2; }
  const int kin = (layer == 0) ? N_D : N_H;
  u32* cnt_own  = cnt + ((size_t)layer * BG + b) * N_T;
  u32* cnt_prev = (layer > 0) ? cnt + ((size_t)(layer - 1) * BG + b) * N_T : nullptr;

  __shared__ u16   WhT[WCOL][N_H];     // [n][k], k rotated by 8*n
  __shared__ u16   WxT[WCOL][N_H];     // layer0 uses only [.][0..63]
  __shared__ float Cbuf[2][ROWS][WCOL + 1];
  __shared__ u32   fastsh;

  // ---- startup handshake: all 24 WGs of bg b on one XCD? ----
  u32 xcc;
  asm volatile("s_getreg_b32 %0, hwreg(HW_REG_XCC_ID)" : "=s"(xcc));
  if (tid == 0) {
    __hip_atomic_fetch_or(&hsk[BG + b], 1u << (xcc & 7), __ATOMIC_RELAXED,
                          __HIP_MEMORY_SCOPE_AGENT);
    asm volatile("s_waitcnt vmcnt(0)" ::: "memory");
    __hip_atomic_fetch_add(&hsk[b], 1u, __ATOMIC_RELAXED, __HIP_MEMORY_SCOPE_AGENT);
  }

  // Stage weight slices (cols j*64..+64) while the handshake propagates.
  for (int e = tid; e < WCOL * N_H; e += 256) {
    int n = e & 63, k = e >> 6;
    WhT[n][(k + 8 * n) & (N_H - 1)] = f2bf(Wh[k * N_H + j * WCOL + n]);
  }
  for (int e = tid; e < WCOL * kin; e += 256) {
    int n = e & 63, k = e >> 6;
    WxT[n][(k + 8 * n) & (kin - 1)] = f2bf(Wx[k * N_H + j * WCOL + n]);
  }
  float bv[4];
#pragma unroll
  for (int n = 0; n < 4; ++n) bv[n] = bias[j * WCOL + n * 16 + l16];

  if (tid == 0) {
    bool f = false;
    u32 it = 0;
    while (rmw_read(&hsk[b]) < (u32)HSK_TGT) {
      __builtin_amdgcn_s_sleep(1);
      if (++it > (1u << 22)) break;
    }
    if (it <= (1u << 22)) {
      u32 m = rmw_read(&hsk[BG + b]);
      f = (m != 0u) && ((m & (m - 1u)) == 0u);
    }
    fastsh = f ? 1u : 0u;
  }
  __syncthreads();
  const bool fast = (fastsh == 1u);

  const int arow = b * ROWS + half * 16 + l16;  // this lane's A-row
  bool dead = false;

  for (int t = 0; t < N_T; ++t) {
    const int par = t & 1;
    f32x4 acc[4] = {{0.f,0.f,0.f,0.f},{0.f,0.f,0.f,0.f},{0.f,0.f,0.f,0.f},{0.f,0.f,0.f,0.f}};

    if (!is_rec) {
      // ---- proj waves: (layer0: x_t@Wx) / (else: h_{l-1}(t)@Wx) -> Cbuf ----
      if (layer == 0) {
        const float* xp = x + ((size_t)arow * N_T + t) * N_D + quad * 8;
        short8 f0 = cvt8(xp), f1 = cvt8(xp + 32);
#pragma unroll
        for (int n = 0; n < 4; ++n) {
          int nl = n * 16 + l16;
          acc[n] = MFMA16(f0, ld8(&WxT[nl][(quad * 8 + 8 * nl) & (N_D - 1)]), acc[n]);
          acc[n] = MFMA16(f1, ld8(&WxT[nl][(32 + quad * 8 + 8 * nl) & (N_D - 1)]), acc[n]);
        }
      } else {
        // wait for layer l-1 to publish h(t)
        if (lane == 0 && !dead) {
          u32* cp = cnt_prev + t;
          u32 it = 0;
          for (;;) {
            u32 v = fast ? rmw_read(cp)
                         : __hip_atomic_load(cp, __ATOMIC_RELAXED, __HIP_MEMORY_SCOPE_AGENT);
            if (v >= (u32)CNT_TGT) break;
            __builtin_amdgcn_s_sleep(1);
            if (++it > (1u << 22)) { dead = true; break; }
          }
        }
        const u16* sp = in_seq + ((size_t)t * N_B + arow) * N_H + quad * 8;
        i32x4 fr[16];
        if (fast) load_frags16_fast(sp, fr);
        else      load_frags16_slow(sp, fr);
#pragma unroll
        for (int kt = 0; kt < 16; ++kt) {
          short8 a = as_s8(fr[kt]);
#pragma unroll
          for (int n = 0; n < 4; ++n) {
            int nl = n * 16 + l16;
            acc[n] = MFMA16(a, ld8(&WxT[nl][(kt * 32 + quad * 8 + 8 * nl) & (N_H - 1)]), acc[n]);
          }
        }
      }
      // write proj partials to Cbuf[par]
      int rb = half * 16 + quad * 4;
#pragma unroll
      for (int n = 0; n < 4; ++n)
#pragma unroll
        for (int r = 0; r < 4; ++r)
          Cbuf[par][rb + r][n * 16 + l16] = acc[n][r];
    } else {
      // ---- rec waves: wait own layer t-1, load A, h@Wh ----
      if (t > 0) {
        if (lane == 0 && !dead) {
          u32* cp = cnt_own + (t - 1);
          u32 it = 0;
          for (;;) {
            u32 v = fast ? rmw_read(cp)
                         : __hip_atomic_load(cp, __ATOMIC_RELAXED, __HIP_MEMORY_SCOPE_AGENT);
            if (v >= (u32)CNT_TGT) break;
            __builtin_amdgcn_s_sleep(1);
            if (++it > (1u << 22)) { dead = true; break; }
          }
        }
        const u16* ap = out_seq + ((size_t)(t - 1) * N_B + arow) * N_H + quad * 8;
        i32x4 fr[16];
        if (fast) load_frags16_fast(ap, fr);
        else      load_frags16_slow(ap, fr);
#pragma unroll
        for (int kt = 0; kt < 16; ++kt) {
          short8 a = as_s8(fr[kt]);
#pragma unroll
          for (int n = 0; n < 4; ++n) {
            int nl = n * 16 + l16;
            acc[n] = MFMA16(a, ld8(&WhT[nl][(kt * 32 + quad * 8 + 8 * nl) & (N_H - 1)]), acc[n]);
          }
        }
      }
    }

    __syncthreads();  // the only per-step barrier: Cbuf[par] ready

    if (is_rec) {
      // ---- combine + tanh + store h + publish ----
      int rb = half * 16 + quad * 4;
      u32 hv[4][4];
#pragma unroll
      for (int n = 0; n < 4; ++n)
#pragma unroll
        for (int r = 0; r < 4; ++r)
          hv[n][r] = (u32)f2bf(fast_tanh(acc[n][r] + Cbuf[par][rb + r][n * 16 + l16] + bv[n]));
      // lane addr: row = b*32 + half*16 + quad*4 (+r), col = j*64 + l16 (+n*16)
      u16* hdst = out_seq + ((size_t)t * N_B + b * ROWS + half * 16 + quad * 4) * N_H
                  + j * WCOL + l16;
      if (fast) {
        asm volatile(
            "global_store_short %0, %1, off sc0\n\t"
            "global_store_short %0, %2, off offset:1024 sc0\n\t"
            "global_store_short %0, %3, off offset:2048 sc0\n\t"
            "global_store_short %0, %4, off offset:3072 sc0\n\t"
            "global_store_short %0, %5, off offset:32 sc0\n\t"
            "global_store_short %0, %6, off offset:1056 sc0\n\t"
            "global_store_short %0, %7, off offset:2080 sc0\n\t"
            "global_store_short %0, %8, off offset:3104 sc0\n\t"
            "global_store_short %0, %9, off offset:64 sc0\n\t"
            "global_store_short %0, %10, off offset:1088 sc0\n\t"
            "global_store_short %0, %11, off offset:2112 sc0\n\t"
            "global_store_short %0, %12, off offset:3136 sc0\n\t"
            "global_store_short %0, %13, off offset:96 sc0\n\t"
            "global_store_short %0, %14, off offset:1120 sc0\n\t"
            "global_store_short %0, %15, off offset:2144 sc0\n\t"
            "global_store_short %0, %16, off offset:3168 sc0"
            :: "v"(hdst),
               "v"(hv[0][0]), "v"(hv[0][1]), "v"(hv[0][2]), "v"(hv[0][3]),
               "v"(hv[1][0]), "v"(hv[1][1]), "v"(hv[1][2]), "v"(hv[1][3]),
               "v"(hv[2][0]), "v"(hv[2][1]), "v"(hv[2][2]), "v"(hv[2][3]),
               "v"(hv[3][0]), "v"(hv[3][1]), "v"(hv[3][2]), "v"(hv[3][3])
            : "memory");
      } else {
        asm volatile(
            "global_store_short %0, %1, off sc0 sc1\n\t"
            "global_store_short %0, %2, off offset:1024 sc0 sc1\n\t"
            "global_store_short %0, %3, off offset:2048 sc0 sc1\n\t"
            "global_store_short %0, %4, off offset:3072 sc0 sc1\n\t"
            "global_store_short %0, %5, off offset:32 sc0 sc1\n\t"
            "global_store_short %0, %6, off offset:1056 sc0 sc1\n\t"
            "global_store_short %0, %7, off offset:2080 sc0 sc1\n\t"
            "global_store_short %0, %8, off offset:3104 sc0 sc1\n\t"
            "global_store_short %0, %9, off offset:64 sc0 sc1\n\t"
            "global_store_short %0, %10, off offset:1088 sc0 sc1\n\t"
            "global_store_short %0, %11, off offset:2112 sc0 sc1\n\t"
            "global_store_short %0, %12, off offset:3136 sc0 sc1\n\t"
            "global_store_short %0, %13, off offset:96 sc0 sc1\n\t"
            "global_store_short %0, %14, off offset:1120 sc0 sc1\n\t"
            "global_store_short %0, %15, off offset:2144 sc0 sc1\n\t"
            "global_store_short %0, %16, off offset:3168 sc0 sc1"
            :: "v"(hdst),
               "v"(hv[0][0]), "v"(hv[0][1]), "v"(hv[0][2]), "v"(hv[0][3]),
               "v"(hv[1][0]), "v"(hv[1][1]), "v"(hv[1][2]), "v"(hv[1][3]),
               "v"(hv[2][0]), "v"(hv[2][1]), "v"(hv[2][2]), "v"(hv[2][3]),
               "v"(hv[3][0]), "v"(hv[3][1]), "v"(hv[3][2]), "v"(hv[3][3])
            : "memory");
      }
      asm volatile("s_waitcnt vmcnt(0)" ::: "memory");
      if (lane == 0) {
        u32* cp = cnt_own + t;
        if (fast) {
          u32 one = 1u;
          asm volatile("global_atomic_add %0, %1, off" :: "v"(cp), "v"(one) : "memory");
        } else {
          __hip_atomic_fetch_add(cp, 1u, __ATOMIC_RELAXED, __HIP_MEMORY_SCOPE_AGENT);
        }
      }
    }
    // no trailing barrier: Cbuf parity + next barrier handle WAR (r8-proven)
  }
}

// out[b] = seq2[T-1][b][:] . Wf + bf
__global__ void head_kernel(const u16* __restrict__ seq2, const float* __restrict__ Wf,
                            const float* __restrict__ bf, float* __restrict__ out) {
  int b    = blockIdx.x;
  int lane = threadIdx.x;  // 64
  const u16* hrow = seq2 + ((size_t)(N_T - 1) * N_B + b) * N_H;
  float s = 0.f;
#pragma unroll
  for (int r = 0; r < N_H / 64; ++r) {
    int idx = lane * 8 + r;
    s += bf2f(hrow[idx]) * Wf[idx];
  }
#pragma unroll
  for (int off = 32; off > 0; off >>= 1) s += __shfl_down(s, off);
  if (lane == 0) out[b] = s + bf[0];
}

extern "C" void kernel_launch(void* const* d_in, const int* in_sizes, int n_in,
                              void* d_out, int out_size, void* d_ws, size_t ws_size,
                              hipStream_t stream) {
  const float* x   = (const float*)d_in[0];
  const float* Wx0 = (const float*)d_in[1];
  const float* Wh0 = (const float*)d_in[2];
  const float* b0  = (const float*)d_in[3];
  const float* Wx1 = (const float*)d_in[4];
  const float* Wh1 = (const float*)d_in[5];
  const float* b1  = (const float*)d_in[6];
  const float* Wx2 = (const float*)d_in[7];
  const float* Wh2 = (const float*)d_in[8];
  const float* b2  = (const float*)d_in[9];
  const float* Wf  = (const float*)d_in[10];
  const float* bf  = (const float*)d_in[11];
  float* out = (float*)d_out;

  const size_t SEQ_BYTES = (size_t)N_T * N_B * N_H * sizeof(u16);  // 67,108,864
  const size_t CNT_U32   = (size_t)LAY * BG * N_T;                 // 6,144
  const size_t HSK_U32   = (size_t)2 * BG;                         // 16
  if (ws_size < 3 * SEQ_BYTES + (CNT_U32 + HSK_U32) * sizeof(u32)) return;

  char* ws  = (char*)d_ws;
  u16* seq0 = (u16*)(ws);
  u16* seq1 = (u16*)(ws + SEQ_BYTES);
  u16* seq2 = (u16*)(ws + 2 * SEQ_BYTES);
  u32* cnt  = (u32*)(ws + 3 * SEQ_BYTES);
  u32* hsk  = cnt + CNT_U32;

  (void)hipMemsetAsync(cnt, 0, (CNT_U32 + HSK_U32) * sizeof(u32), stream);

  rnn_pipe<<<LAY * BG * CGS, 256, 0, stream>>>(x, Wx0, Wh0, b0, Wx1, Wh1, b1,
                                               Wx2, Wh2, b2, seq0, seq1, seq2,
                                               cnt, hsk);
  head_kernel<<<N_B, 64, 0, stream>>>(seq2, Wf, bf, out);
}